// Round 5
// baseline (210.334 us; speedup 1.0000x reference)
//
#include <hip/hip_runtime.h>

// GAT layer: B=8, N=2048, Fin=Fout=64
// k1 : Wh=h@W (MFMA) stored in MFMA-B-fragment order (whF) + s,t fp32. grid 256.
// k2 : masked softmax + P@Wh, adj loaded DIRECTLY in the s-loop (no bitmask pass).
//      16 rows/block (grid 1024), __launch_bounds__(256,4) -> VGPR<=128, 16 waves/CU
//      for HBM latency hiding of the 134-MB adj stream (was 8 waves/CU at half BW).
//      p = adj ? max(al*e^t, cl*e^{a t}) : 0; z via a 5th "ones-column" MFMA.

#define ALPHA 0.2f

typedef __attribute__((ext_vector_type(8))) short  short8;
typedef __attribute__((ext_vector_type(4))) float  f32x4;

static __device__ __forceinline__ unsigned short f2bf(float f) {
    unsigned u = __builtin_bit_cast(unsigned, f);
    u += 0x7fffu + ((u >> 16) & 1u);   // round-to-nearest-even
    return (unsigned short)(u >> 16);
}

// two f32 -> packed bf16x2 (lo in low half), round-half-up
static __device__ __forceinline__ unsigned pack_bf2(float lo, float hi) {
    unsigned ulo = __builtin_bit_cast(unsigned, lo) + 0x8000u;
    unsigned uhi = __builtin_bit_cast(unsigned, hi) + 0x8000u;
    return __builtin_amdgcn_perm(uhi, ulo, 0x07060302);
}

// ---------------- k1: Wh + s,t (unchanged) ----------------
__global__ __launch_bounds__(256) void k1(
    const float* __restrict__ h, const float* __restrict__ W,
    const float* __restrict__ a, uint4* __restrict__ whF,
    float* __restrict__ sw, float* __restrict__ tw)
{
    __shared__ float W_l[64 * 65];
    __shared__ float wa[128];
    __shared__ float tile[4 * 16 * 65];

    const int tid = threadIdx.x;
    const int lane = tid & 63, wv = tid >> 6;
    const int im   = lane & 15, kq = lane >> 4;

    #pragma unroll
    for (int k = 0; k < 16; ++k) {
        int e = tid + 256 * k;
        W_l[(e >> 6) * 65 + (e & 63)] = W[e];
    }
    __syncthreads();

    if (tid < 128) {
        int f = tid & 63;
        const float* ap = a + (tid >> 6) * 64;
        float acc = 0.f;
        #pragma unroll 8
        for (int o = 0; o < 64; ++o) acc += W_l[f * 65 + o] * ap[o];
        wa[tid] = acc;
    }
    __syncthreads();

    short8 bf[4][2];
    #pragma unroll
    for (int nb = 0; nb < 4; ++nb)
        #pragma unroll
        for (int ks = 0; ks < 2; ++ks)
            #pragma unroll
            for (int u = 0; u < 8; ++u)
                bf[nb][ks][u] = (short)f2bf(W_l[(ks * 32 + kq * 8 + u) * 65 + nb * 16 + im]);

    const int row0 = blockIdx.x * 64 + wv * 16;
    const float* hrow = h + (size_t)(row0 + im) * 64;

    float hv[2][8];
    short8 af[2];
    float sp = 0.f, tp = 0.f;
    #pragma unroll
    for (int ks = 0; ks < 2; ++ks) {
        float4 A = *(const float4*)(hrow + ks * 32 + kq * 8);
        float4 Bv = *(const float4*)(hrow + ks * 32 + kq * 8 + 4);
        hv[ks][0] = A.x;  hv[ks][1] = A.y;  hv[ks][2] = A.z;  hv[ks][3] = A.w;
        hv[ks][4] = Bv.x; hv[ks][5] = Bv.y; hv[ks][6] = Bv.z; hv[ks][7] = Bv.w;
        #pragma unroll
        for (int u = 0; u < 8; ++u) {
            int f = ks * 32 + kq * 8 + u;
            sp += hv[ks][u] * wa[f];
            tp += hv[ks][u] * wa[64 + f];
            af[ks][u] = (short)f2bf(hv[ks][u]);
        }
    }
    sp += __shfl_xor(sp, 16, 64); sp += __shfl_xor(sp, 32, 64);
    tp += __shfl_xor(tp, 16, 64); tp += __shfl_xor(tp, 32, 64);
    if (lane < 16) {
        sw[row0 + lane] = sp;
        tw[row0 + lane] = tp;
    }

    f32x4 acc[4] = {{0.f,0.f,0.f,0.f},{0.f,0.f,0.f,0.f},{0.f,0.f,0.f,0.f},{0.f,0.f,0.f,0.f}};
    #pragma unroll
    for (int ks = 0; ks < 2; ++ks)
        #pragma unroll
        for (int nb = 0; nb < 4; ++nb)
            acc[nb] = __builtin_amdgcn_mfma_f32_16x16x32_bf16(af[ks], bf[nb][ks], acc[nb], 0, 0, 0);

    #pragma unroll
    for (int nb = 0; nb < 4; ++nb)
        #pragma unroll
        for (int r = 0; r < 4; ++r)
            tile[wv * 1040 + (kq * 4 + r) * 65 + nb * 16 + im] = acc[nb][r];
    __syncthreads();

    // ---- store Wh in MFMA-B-fragment order ----
    {
        const int blk_row0 = blockIdx.x * 64;
        const int bb2 = blk_row0 >> 11;
        const int c_base = (blk_row0 & 2047) >> 5;
        #pragma unroll
        for (int k = 0; k < 2; ++k) {
            int e = tid + 256 * k;
            int l = e & 63, ot = (e >> 6) & 3, cl_ = e >> 8;
            int o = ot * 16 + (l & 15);
            int jb = cl_ * 32 + (l >> 4) * 8;
            unsigned d0, d1, d2, d3;
            {
                int j0 = jb;
                d0 = pack_bf2(tile[(j0 >> 4) * 1040 + (j0 & 15) * 65 + o],
                              tile[(j0 >> 4) * 1040 + ((j0 & 15) + 1) * 65 + o]);
                j0 = jb + 2;
                d1 = pack_bf2(tile[(j0 >> 4) * 1040 + (j0 & 15) * 65 + o],
                              tile[(j0 >> 4) * 1040 + ((j0 & 15) + 1) * 65 + o]);
                j0 = jb + 4;
                d2 = pack_bf2(tile[(j0 >> 4) * 1040 + (j0 & 15) * 65 + o],
                              tile[(j0 >> 4) * 1040 + ((j0 & 15) + 1) * 65 + o]);
                j0 = jb + 6;
                d3 = pack_bf2(tile[(j0 >> 4) * 1040 + (j0 & 15) * 65 + o],
                              tile[(j0 >> 4) * 1040 + ((j0 & 15) + 1) * 65 + o]);
            }
            uint4 val = {d0, d1, d2, d3};
            whF[(size_t)(((bb2 * 64 + c_base + cl_) * 4 + ot)) * 64 + l] = val;
        }
    }
}

// ---------------- k2: masked softmax + P@Wh ----------------
// grid 1024 (b, i0: 16 rows) x 256 thr; wave = 512-j stripe.
// adj read directly: per iter s, lane (im,kq) loads 2x int4 for its row; the 4 kq
// lanes x 2 loads tile a contiguous 128-B line per row -> HBM-efficient stream.
__global__ __launch_bounds__(256, 4) void k2_attn(
    const int* __restrict__ adj, const uint4* __restrict__ whF,
    const float* __restrict__ sw, const float* __restrict__ tw,
    float* __restrict__ out)
{
    __shared__ float eB[2048];
    __shared__ float eD[2048];
    __shared__ float cpart[4 * 1088];   // [wv][row 0..15][col 0..67]; col 64 = z

    const int tid  = threadIdx.x;
    const int lane = tid & 63, wv = tid >> 6;
    const int im   = lane & 15, kq = lane >> 4;
    const int b    = blockIdx.x >> 7;
    const int i0   = (blockIdx.x & 127) << 4;

    // exp tables: eB[j]=exp(t_j), eD[j]=exp(ALPHA*t_j)
    {
        const float4* tp4 = (const float4*)(tw + (size_t)b * 2048);
        float4 t0 = tp4[tid], t1 = tp4[tid + 256];
        float4 e0 = {__expf(t0.x), __expf(t0.y), __expf(t0.z), __expf(t0.w)};
        float4 e1 = {__expf(t1.x), __expf(t1.y), __expf(t1.z), __expf(t1.w)};
        float4 f0 = {__expf(ALPHA*t0.x), __expf(ALPHA*t0.y), __expf(ALPHA*t0.z), __expf(ALPHA*t0.w)};
        float4 f1 = {__expf(ALPHA*t1.x), __expf(ALPHA*t1.y), __expf(ALPHA*t1.z), __expf(ALPHA*t1.w)};
        *(float4*)&eB[tid * 4] = e0;  *(float4*)&eB[(tid + 256) * 4] = e1;
        *(float4*)&eD[tid * 4] = f0;  *(float4*)&eD[(tid + 256) * 4] = f1;
    }

    const int j00 = wv * 512 + kq * 8;
    // adj row pointer (int4 granularity). iter s uses indices s*8 and s*8+1.
    const int4* arow0 = (const int4*)(adj + (size_t)(b * 2048 + i0 + im) * 2048) + (j00 >> 2);

    const float sl0 = sw[b * 2048 + i0 + im];
    const float al0 = __expf(sl0), cl0 = __expf(ALPHA * sl0);

    const uint4* wbase = whF + (size_t)((b * 64 + wv * 16) * 4) * 64 + lane;

    // ones-column B-fragment: B[k][0] = 1, else 0  ->  D[i][0] = row sum
    short8 onesf;
    {
        const short ov = (im == 0) ? (short)0x3F80 : (short)0;
        #pragma unroll
        for (int u = 0; u < 8; ++u) onesf[u] = ov;
    }

    __syncthreads();

    f32x4 acc0 = {0.f,0.f,0.f,0.f}, acc1 = {0.f,0.f,0.f,0.f};
    f32x4 acc2 = {0.f,0.f,0.f,0.f}, acc3 = {0.f,0.f,0.f,0.f};
    f32x4 az0  = {0.f,0.f,0.f,0.f};

    #pragma unroll
    for (int s = 0; s < 16; ++s) {
        const uint4 w0 = wbase[(s * 4 + 0) * 64];
        const uint4 w1 = wbase[(s * 4 + 1) * 64];
        const uint4 w2 = wbase[(s * 4 + 2) * 64];
        const uint4 w3 = wbase[(s * 4 + 3) * 64];

        const int4 a0A = arow0[s * 8];
        const int4 a0B = arow0[s * 8 + 1];

        const float4 bA  = *(const float4*)&eB[j00 + s * 32];
        const float4 bBv = *(const float4*)&eB[j00 + s * 32 + 4];
        const float4 dA  = *(const float4*)&eD[j00 + s * 32];
        const float4 dBv = *(const float4*)&eD[j00 + s * 32 + 4];

        // p = adj ? max(al*e^t, cl*e^{a t}) : 0
        float p0 = fmaxf(al0 * bA.x,  cl0 * dA.x);   p0 = a0A.x ? p0 : 0.f;
        float p1 = fmaxf(al0 * bA.y,  cl0 * dA.y);   p1 = a0A.y ? p1 : 0.f;
        float p2 = fmaxf(al0 * bA.z,  cl0 * dA.z);   p2 = a0A.z ? p2 : 0.f;
        float p3 = fmaxf(al0 * bA.w,  cl0 * dA.w);   p3 = a0A.w ? p3 : 0.f;
        float p4 = fmaxf(al0 * bBv.x, cl0 * dBv.x);  p4 = a0B.x ? p4 : 0.f;
        float p5 = fmaxf(al0 * bBv.y, cl0 * dBv.y);  p5 = a0B.y ? p5 : 0.f;
        float p6 = fmaxf(al0 * bBv.z, cl0 * dBv.z);  p6 = a0B.z ? p6 : 0.f;
        float p7 = fmaxf(al0 * bBv.w, cl0 * dBv.w);  p7 = a0B.w ? p7 : 0.f;

        int4 ai0;
        ai0.x = (int)pack_bf2(p0, p1);
        ai0.y = (int)pack_bf2(p2, p3);
        ai0.z = (int)pack_bf2(p4, p5);
        ai0.w = (int)pack_bf2(p6, p7);
        const short8 af0 = __builtin_bit_cast(short8, ai0);

        acc0 = __builtin_amdgcn_mfma_f32_16x16x32_bf16(af0, __builtin_bit_cast(short8, w0), acc0, 0, 0, 0);
        acc1 = __builtin_amdgcn_mfma_f32_16x16x32_bf16(af0, __builtin_bit_cast(short8, w1), acc1, 0, 0, 0);
        acc2 = __builtin_amdgcn_mfma_f32_16x16x32_bf16(af0, __builtin_bit_cast(short8, w2), acc2, 0, 0, 0);
        acc3 = __builtin_amdgcn_mfma_f32_16x16x32_bf16(af0, __builtin_bit_cast(short8, w3), acc3, 0, 0, 0);
        az0  = __builtin_amdgcn_mfma_f32_16x16x32_bf16(af0, onesf, az0, 0, 0, 0);
    }

    #pragma unroll
    for (int r = 0; r < 4; ++r) {
        const int row = kq * 4 + r;
        float* cp0 = &cpart[wv * 1088 + row * 68];
        cp0[ 0 + im] = acc0[r];
        cp0[16 + im] = acc1[r];
        cp0[32 + im] = acc2[r];
        cp0[48 + im] = acc3[r];
        if (im == 0) cp0[64] = az0[r];
    }
    __syncthreads();

    // epilogue: 1 float4 output per thread (16 rows x 64 cols / 4 = 256)
    {
        const int i  = tid >> 4;               // 0..15
        const int oc = (tid & 15) << 2;        // 0,4,..,60
        const float4 s0 = *(const float4*)&cpart[0 * 1088 + i * 68 + oc];
        const float4 s1 = *(const float4*)&cpart[1 * 1088 + i * 68 + oc];
        const float4 s2 = *(const float4*)&cpart[2 * 1088 + i * 68 + oc];
        const float4 s3 = *(const float4*)&cpart[3 * 1088 + i * 68 + oc];
        float z = cpart[0 * 1088 + i * 68 + 64] + cpart[1 * 1088 + i * 68 + 64]
                + cpart[2 * 1088 + i * 68 + 64] + cpart[3 * 1088 + i * 68 + 64];
        if (z == 0.f) z = 1.f;
        const float inv = 1.f / z;
        float4 rv;
        rv.x = ((s0.x + s1.x) + (s2.x + s3.x)) * inv;
        rv.y = ((s0.y + s1.y) + (s2.y + s3.y)) * inv;
        rv.z = ((s0.z + s1.z) + (s2.z + s3.z)) * inv;
        rv.w = ((s0.w + s1.w) + (s2.w + s3.w)) * inv;
        rv.x = rv.x > 0.f ? rv.x : expm1f(rv.x);
        rv.y = rv.y > 0.f ? rv.y : expm1f(rv.y);
        rv.z = rv.z > 0.f ? rv.z : expm1f(rv.z);
        rv.w = rv.w > 0.f ? rv.w : expm1f(rv.w);
        *(float4*)(out + ((size_t)(b * 2048 + i0 + i)) * 64 + oc) = rv;
    }
}

extern "C" void kernel_launch(void* const* d_in, const int* in_sizes, int n_in,
                              void* d_out, int out_size, void* d_ws, size_t ws_size,
                              hipStream_t stream) {
    const float* h   = (const float*)d_in[0];
    const int*   adj = (const int*)d_in[1];
    const float* W   = (const float*)d_in[2];
    const float* a   = (const float*)d_in[3];
    float* out = (float*)d_out;

    uint4* whF = (uint4*)d_ws;                                           // 2 MiB
    float* sw  = (float*)((char*)d_ws + 2097152);                        // 64 KiB
    float* tw  = (float*)((char*)d_ws + 2097152 + 65536);                // 64 KiB

    hipLaunchKernelGGL(k1, dim3(256), dim3(256), 0, stream, h, W, a, whF, sw, tw);
    hipLaunchKernelGGL(k2_attn, dim3(1024), dim3(256), 0, stream,
                       adj, whF, sw, tw, out);
}

// Round 6
// 205.470 us; speedup vs baseline: 1.0237x; 1.0237x over previous
//
#include <hip/hip_runtime.h>

// GAT layer: B=8, N=2048, Fin=Fout=64
// k1 : Wh=h@W (MFMA) stored in MFMA-B-fragment order (whF) + s,t fp32. grid 256.
// k2 : masked softmax + P@Wh, 32 rows/block (grid 512, LB(256,2) -- the 204.5us config).
//      adj is staged through per-wave LDS: 4 coalesced int4 loads/iter (full 128-B
//      lines, 8 requests/instr) replace the 16-way-scattered per-lane loads
//      (64 requests/instr). Each lane then ds_read_b128's its (im,kq) fragment.
//      p = adj ? max(al*e^t, cl*e^{a t}) : 0; z via a 5th "ones-column" MFMA.

#define ALPHA 0.2f

typedef __attribute__((ext_vector_type(8))) short  short8;
typedef __attribute__((ext_vector_type(4))) float  f32x4;

static __device__ __forceinline__ unsigned short f2bf(float f) {
    unsigned u = __builtin_bit_cast(unsigned, f);
    u += 0x7fffu + ((u >> 16) & 1u);   // round-to-nearest-even
    return (unsigned short)(u >> 16);
}

// two f32 -> packed bf16x2 (lo in low half), round-half-up
static __device__ __forceinline__ unsigned pack_bf2(float lo, float hi) {
    unsigned ulo = __builtin_bit_cast(unsigned, lo) + 0x8000u;
    unsigned uhi = __builtin_bit_cast(unsigned, hi) + 0x8000u;
    return __builtin_amdgcn_perm(uhi, ulo, 0x07060302);
}

// ---------------- k1: Wh + s,t (unchanged) ----------------
__global__ __launch_bounds__(256) void k1(
    const float* __restrict__ h, const float* __restrict__ W,
    const float* __restrict__ a, uint4* __restrict__ whF,
    float* __restrict__ sw, float* __restrict__ tw)
{
    __shared__ float W_l[64 * 65];
    __shared__ float wa[128];
    __shared__ float tile[4 * 16 * 65];

    const int tid = threadIdx.x;
    const int lane = tid & 63, wv = tid >> 6;
    const int im   = lane & 15, kq = lane >> 4;

    #pragma unroll
    for (int k = 0; k < 16; ++k) {
        int e = tid + 256 * k;
        W_l[(e >> 6) * 65 + (e & 63)] = W[e];
    }
    __syncthreads();

    if (tid < 128) {
        int f = tid & 63;
        const float* ap = a + (tid >> 6) * 64;
        float acc = 0.f;
        #pragma unroll 8
        for (int o = 0; o < 64; ++o) acc += W_l[f * 65 + o] * ap[o];
        wa[tid] = acc;
    }
    __syncthreads();

    short8 bf[4][2];
    #pragma unroll
    for (int nb = 0; nb < 4; ++nb)
        #pragma unroll
        for (int ks = 0; ks < 2; ++ks)
            #pragma unroll
            for (int u = 0; u < 8; ++u)
                bf[nb][ks][u] = (short)f2bf(W_l[(ks * 32 + kq * 8 + u) * 65 + nb * 16 + im]);

    const int row0 = blockIdx.x * 64 + wv * 16;
    const float* hrow = h + (size_t)(row0 + im) * 64;

    float hv[2][8];
    short8 af[2];
    float sp = 0.f, tp = 0.f;
    #pragma unroll
    for (int ks = 0; ks < 2; ++ks) {
        float4 A = *(const float4*)(hrow + ks * 32 + kq * 8);
        float4 Bv = *(const float4*)(hrow + ks * 32 + kq * 8 + 4);
        hv[ks][0] = A.x;  hv[ks][1] = A.y;  hv[ks][2] = A.z;  hv[ks][3] = A.w;
        hv[ks][4] = Bv.x; hv[ks][5] = Bv.y; hv[ks][6] = Bv.z; hv[ks][7] = Bv.w;
        #pragma unroll
        for (int u = 0; u < 8; ++u) {
            int f = ks * 32 + kq * 8 + u;
            sp += hv[ks][u] * wa[f];
            tp += hv[ks][u] * wa[64 + f];
            af[ks][u] = (short)f2bf(hv[ks][u]);
        }
    }
    sp += __shfl_xor(sp, 16, 64); sp += __shfl_xor(sp, 32, 64);
    tp += __shfl_xor(tp, 16, 64); tp += __shfl_xor(tp, 32, 64);
    if (lane < 16) {
        sw[row0 + lane] = sp;
        tw[row0 + lane] = tp;
    }

    f32x4 acc[4] = {{0.f,0.f,0.f,0.f},{0.f,0.f,0.f,0.f},{0.f,0.f,0.f,0.f},{0.f,0.f,0.f,0.f}};
    #pragma unroll
    for (int ks = 0; ks < 2; ++ks)
        #pragma unroll
        for (int nb = 0; nb < 4; ++nb)
            acc[nb] = __builtin_amdgcn_mfma_f32_16x16x32_bf16(af[ks], bf[nb][ks], acc[nb], 0, 0, 0);

    #pragma unroll
    for (int nb = 0; nb < 4; ++nb)
        #pragma unroll
        for (int r = 0; r < 4; ++r)
            tile[wv * 1040 + (kq * 4 + r) * 65 + nb * 16 + im] = acc[nb][r];
    __syncthreads();

    // ---- store Wh in MFMA-B-fragment order ----
    {
        const int blk_row0 = blockIdx.x * 64;
        const int bb2 = blk_row0 >> 11;
        const int c_base = (blk_row0 & 2047) >> 5;
        #pragma unroll
        for (int k = 0; k < 2; ++k) {
            int e = tid + 256 * k;
            int l = e & 63, ot = (e >> 6) & 3, cl_ = e >> 8;
            int o = ot * 16 + (l & 15);
            int jb = cl_ * 32 + (l >> 4) * 8;
            unsigned d0, d1, d2, d3;
            {
                int j0 = jb;
                d0 = pack_bf2(tile[(j0 >> 4) * 1040 + (j0 & 15) * 65 + o],
                              tile[(j0 >> 4) * 1040 + ((j0 & 15) + 1) * 65 + o]);
                j0 = jb + 2;
                d1 = pack_bf2(tile[(j0 >> 4) * 1040 + (j0 & 15) * 65 + o],
                              tile[(j0 >> 4) * 1040 + ((j0 & 15) + 1) * 65 + o]);
                j0 = jb + 4;
                d2 = pack_bf2(tile[(j0 >> 4) * 1040 + (j0 & 15) * 65 + o],
                              tile[(j0 >> 4) * 1040 + ((j0 & 15) + 1) * 65 + o]);
                j0 = jb + 6;
                d3 = pack_bf2(tile[(j0 >> 4) * 1040 + (j0 & 15) * 65 + o],
                              tile[(j0 >> 4) * 1040 + ((j0 & 15) + 1) * 65 + o]);
            }
            uint4 val = {d0, d1, d2, d3};
            whF[(size_t)(((bb2 * 64 + c_base + cl_) * 4 + ot)) * 64 + l] = val;
        }
    }
}

// ---------------- k2: masked softmax + P@Wh ----------------
// grid 512 (b, i0: 32 rows) x 256 thr; wave = 512-j stripe, 2 row-tiles of 16.
// adj staged via LDS: iter s, wave wv needs rows i0..i0+31 x bytes
// [wv*2048 + s*128, +128). Coalesced: instr k, lane l reads row k*8+(l>>3),
// bytes (l&7)*16 (beat = 2 rows x 128 B = full lines). Row stride padded to
// 144 B (9 uint4) -> <=2-way LDS bank aliasing on both write and read.
__global__ __launch_bounds__(256, 2) void k2_attn(
    const int* __restrict__ adj, const uint4* __restrict__ whF,
    const float* __restrict__ sw, const float* __restrict__ tw,
    float* __restrict__ out)
{
    __shared__ float eB[2048];
    __shared__ float eD[2048];
    __shared__ uint4 astage[4][32][9];  // per-wave staging, 18.4 KB
    __shared__ float cpart[4 * 2176];   // [wv][row 0..31][col 0..67]; col 64 = z

    const int tid  = threadIdx.x;
    const int lane = tid & 63, wv = tid >> 6;
    const int im   = lane & 15, kq = lane >> 4;
    const int lrow = lane >> 3;         // 0..7
    const int lcol = lane & 7;          // 0..7
    const int b    = blockIdx.x >> 6;
    const int i0   = (blockIdx.x & 63) << 5;

    // exp tables: eB[j]=exp(t_j), eD[j]=exp(ALPHA*t_j)
    {
        const float4* tp4 = (const float4*)(tw + (size_t)b * 2048);
        float4 t0 = tp4[tid], t1 = tp4[tid + 256];
        float4 e0 = {__expf(t0.x), __expf(t0.y), __expf(t0.z), __expf(t0.w)};
        float4 e1 = {__expf(t1.x), __expf(t1.y), __expf(t1.z), __expf(t1.w)};
        float4 f0 = {__expf(ALPHA*t0.x), __expf(ALPHA*t0.y), __expf(ALPHA*t0.z), __expf(ALPHA*t0.w)};
        float4 f1 = {__expf(ALPHA*t1.x), __expf(ALPHA*t1.y), __expf(ALPHA*t1.z), __expf(ALPHA*t1.w)};
        *(float4*)&eB[tid * 4] = e0;  *(float4*)&eB[(tid + 256) * 4] = e1;
        *(float4*)&eD[tid * 4] = f0;  *(float4*)&eD[(tid + 256) * 4] = f1;
    }

    const int j00 = wv * 512 + kq * 8;
    // coalesced adj pointer: row i0+lrow, int4 col wv*128 + lcol.
    // iter s adds s*8; row +8 adds 4096.
    const int4* aco = (const int4*)adj
        + (size_t)(b * 2048 + i0 + lrow) * 512 + wv * 128 + lcol;

    const float sl0 = sw[b * 2048 + i0 + im];
    const float sl1 = sw[b * 2048 + i0 + 16 + im];
    const float al0 = __expf(sl0), cl0 = __expf(ALPHA * sl0);
    const float al1 = __expf(sl1), cl1 = __expf(ALPHA * sl1);

    const uint4* wbase = whF + (size_t)((b * 64 + wv * 16) * 4) * 64 + lane;

    // ones-column B-fragment: B[k][0] = 1, else 0  ->  D[i][0] = row sum
    short8 onesf;
    {
        const short ov = (im == 0) ? (short)0x3F80 : (short)0;
        #pragma unroll
        for (int u = 0; u < 8; ++u) onesf[u] = ov;
    }

    __syncthreads();

    f32x4 acc0 = {0.f,0.f,0.f,0.f}, acc1 = {0.f,0.f,0.f,0.f};
    f32x4 acc2 = {0.f,0.f,0.f,0.f}, acc3 = {0.f,0.f,0.f,0.f};
    f32x4 acc4 = {0.f,0.f,0.f,0.f}, acc5 = {0.f,0.f,0.f,0.f};
    f32x4 acc6 = {0.f,0.f,0.f,0.f}, acc7 = {0.f,0.f,0.f,0.f};
    f32x4 az0  = {0.f,0.f,0.f,0.f}, az1  = {0.f,0.f,0.f,0.f};

    #pragma unroll
    for (int s = 0; s < 16; ++s) {
        // ---- stage this wave's 4 KB adj slice, coalesced (full 128-B lines) ----
        const int4 g0 = aco[s * 8];
        const int4 g1 = aco[s * 8 +  4096];
        const int4 g2 = aco[s * 8 +  8192];
        const int4 g3 = aco[s * 8 + 12288];
        *(int4*)&astage[wv][lrow     ][lcol] = g0;
        *(int4*)&astage[wv][lrow +  8][lcol] = g1;
        *(int4*)&astage[wv][lrow + 16][lcol] = g2;
        *(int4*)&astage[wv][lrow + 24][lcol] = g3;
        // per-wave region + in-order DS execution within a wave: no barrier needed.

        const uint4 w0 = wbase[(s * 4 + 0) * 64];
        const uint4 w1 = wbase[(s * 4 + 1) * 64];
        const uint4 w2 = wbase[(s * 4 + 2) * 64];
        const uint4 w3 = wbase[(s * 4 + 3) * 64];

        const int4 a0A = *(const int4*)&astage[wv][im     ][kq * 2];
        const int4 a0B = *(const int4*)&astage[wv][im     ][kq * 2 + 1];
        const int4 a1A = *(const int4*)&astage[wv][im + 16][kq * 2];
        const int4 a1B = *(const int4*)&astage[wv][im + 16][kq * 2 + 1];

        const float4 bA  = *(const float4*)&eB[j00 + s * 32];
        const float4 bBv = *(const float4*)&eB[j00 + s * 32 + 4];
        const float4 dA  = *(const float4*)&eD[j00 + s * 32];
        const float4 dBv = *(const float4*)&eD[j00 + s * 32 + 4];

        // tile 0 (rows i0..i0+15):  p = adj ? max(al*e^t, cl*e^{a t}) : 0
        float p0 = fmaxf(al0 * bA.x,  cl0 * dA.x);   p0 = a0A.x ? p0 : 0.f;
        float p1 = fmaxf(al0 * bA.y,  cl0 * dA.y);   p1 = a0A.y ? p1 : 0.f;
        float p2 = fmaxf(al0 * bA.z,  cl0 * dA.z);   p2 = a0A.z ? p2 : 0.f;
        float p3 = fmaxf(al0 * bA.w,  cl0 * dA.w);   p3 = a0A.w ? p3 : 0.f;
        float p4 = fmaxf(al0 * bBv.x, cl0 * dBv.x);  p4 = a0B.x ? p4 : 0.f;
        float p5 = fmaxf(al0 * bBv.y, cl0 * dBv.y);  p5 = a0B.y ? p5 : 0.f;
        float p6 = fmaxf(al0 * bBv.z, cl0 * dBv.z);  p6 = a0B.z ? p6 : 0.f;
        float p7 = fmaxf(al0 * bBv.w, cl0 * dBv.w);  p7 = a0B.w ? p7 : 0.f;

        int4 ai0;
        ai0.x = (int)pack_bf2(p0, p1);
        ai0.y = (int)pack_bf2(p2, p3);
        ai0.z = (int)pack_bf2(p4, p5);
        ai0.w = (int)pack_bf2(p6, p7);
        const short8 af0 = __builtin_bit_cast(short8, ai0);

        // tile 1 (rows i0+16..i0+31)
        float q0 = fmaxf(al1 * bA.x,  cl1 * dA.x);   q0 = a1A.x ? q0 : 0.f;
        float q1 = fmaxf(al1 * bA.y,  cl1 * dA.y);   q1 = a1A.y ? q1 : 0.f;
        float q2 = fmaxf(al1 * bA.z,  cl1 * dA.z);   q2 = a1A.z ? q2 : 0.f;
        float q3 = fmaxf(al1 * bA.w,  cl1 * dA.w);   q3 = a1A.w ? q3 : 0.f;
        float q4 = fmaxf(al1 * bBv.x, cl1 * dBv.x);  q4 = a1B.x ? q4 : 0.f;
        float q5 = fmaxf(al1 * bBv.y, cl1 * dBv.y);  q5 = a1B.y ? q5 : 0.f;
        float q6 = fmaxf(al1 * bBv.z, cl1 * dBv.z);  q6 = a1B.z ? q6 : 0.f;
        float q7 = fmaxf(al1 * bBv.w, cl1 * dBv.w);  q7 = a1B.w ? q7 : 0.f;

        int4 ai1;
        ai1.x = (int)pack_bf2(q0, q1);
        ai1.y = (int)pack_bf2(q2, q3);
        ai1.z = (int)pack_bf2(q4, q5);
        ai1.w = (int)pack_bf2(q6, q7);
        const short8 af1 = __builtin_bit_cast(short8, ai1);

        acc0 = __builtin_amdgcn_mfma_f32_16x16x32_bf16(af0, __builtin_bit_cast(short8, w0), acc0, 0, 0, 0);
        acc1 = __builtin_amdgcn_mfma_f32_16x16x32_bf16(af0, __builtin_bit_cast(short8, w1), acc1, 0, 0, 0);
        acc2 = __builtin_amdgcn_mfma_f32_16x16x32_bf16(af0, __builtin_bit_cast(short8, w2), acc2, 0, 0, 0);
        acc3 = __builtin_amdgcn_mfma_f32_16x16x32_bf16(af0, __builtin_bit_cast(short8, w3), acc3, 0, 0, 0);
        az0  = __builtin_amdgcn_mfma_f32_16x16x32_bf16(af0, onesf, az0, 0, 0, 0);

        acc4 = __builtin_amdgcn_mfma_f32_16x16x32_bf16(af1, __builtin_bit_cast(short8, w0), acc4, 0, 0, 0);
        acc5 = __builtin_amdgcn_mfma_f32_16x16x32_bf16(af1, __builtin_bit_cast(short8, w1), acc5, 0, 0, 0);
        acc6 = __builtin_amdgcn_mfma_f32_16x16x32_bf16(af1, __builtin_bit_cast(short8, w2), acc6, 0, 0, 0);
        acc7 = __builtin_amdgcn_mfma_f32_16x16x32_bf16(af1, __builtin_bit_cast(short8, w3), acc7, 0, 0, 0);
        az1  = __builtin_amdgcn_mfma_f32_16x16x32_bf16(af1, onesf, az1, 0, 0, 0);
    }

    #pragma unroll
    for (int r = 0; r < 4; ++r) {
        const int row = kq * 4 + r;
        float* cp0 = &cpart[wv * 2176 + row * 68];
        cp0[ 0 + im] = acc0[r];
        cp0[16 + im] = acc1[r];
        cp0[32 + im] = acc2[r];
        cp0[48 + im] = acc3[r];
        float* cp1 = &cpart[wv * 2176 + (16 + row) * 68];
        cp1[ 0 + im] = acc4[r];
        cp1[16 + im] = acc5[r];
        cp1[32 + im] = acc6[r];
        cp1[48 + im] = acc7[r];
        if (im == 0) { cp0[64] = az0[r]; cp1[64] = az1[r]; }
    }
    __syncthreads();

    // epilogue: 2 float4 outputs per thread
    #pragma unroll
    for (int k = 0; k < 2; ++k) {
        const int idx4 = tid + 256 * k;        // 0..511
        const int i  = idx4 >> 4;              // 0..31
        const int oc = (idx4 & 15) << 2;       // 0,4,..,60
        const float4 s0 = *(const float4*)&cpart[0 * 2176 + i * 68 + oc];
        const float4 s1 = *(const float4*)&cpart[1 * 2176 + i * 68 + oc];
        const float4 s2 = *(const float4*)&cpart[2 * 2176 + i * 68 + oc];
        const float4 s3 = *(const float4*)&cpart[3 * 2176 + i * 68 + oc];
        float z = cpart[0 * 2176 + i * 68 + 64] + cpart[1 * 2176 + i * 68 + 64]
                + cpart[2 * 2176 + i * 68 + 64] + cpart[3 * 2176 + i * 68 + 64];
        if (z == 0.f) z = 1.f;
        const float inv = 1.f / z;
        float4 rv;
        rv.x = ((s0.x + s1.x) + (s2.x + s3.x)) * inv;
        rv.y = ((s0.y + s1.y) + (s2.y + s3.y)) * inv;
        rv.z = ((s0.z + s1.z) + (s2.z + s3.z)) * inv;
        rv.w = ((s0.w + s1.w) + (s2.w + s3.w)) * inv;
        rv.x = rv.x > 0.f ? rv.x : expm1f(rv.x);
        rv.y = rv.y > 0.f ? rv.y : expm1f(rv.y);
        rv.z = rv.z > 0.f ? rv.z : expm1f(rv.z);
        rv.w = rv.w > 0.f ? rv.w : expm1f(rv.w);
        *(float4*)(out + ((size_t)(b * 2048 + i0 + i)) * 64 + oc) = rv;
    }
}

extern "C" void kernel_launch(void* const* d_in, const int* in_sizes, int n_in,
                              void* d_out, int out_size, void* d_ws, size_t ws_size,
                              hipStream_t stream) {
    const float* h   = (const float*)d_in[0];
    const int*   adj = (const int*)d_in[1];
    const float* W   = (const float*)d_in[2];
    const float* a   = (const float*)d_in[3];
    float* out = (float*)d_out;

    uint4* whF = (uint4*)d_ws;                                           // 2 MiB
    float* sw  = (float*)((char*)d_ws + 2097152);                        // 64 KiB
    float* tw  = (float*)((char*)d_ws + 2097152 + 65536);                // 64 KiB

    hipLaunchKernelGGL(k1, dim3(256), dim3(256), 0, stream, h, W, a, whF, sw, tw);
    hipLaunchKernelGGL(k2_attn, dim3(512), dim3(256), 0, stream,
                       adj, whF, sw, tw, out);
}

// Round 8
// 205.432 us; speedup vs baseline: 1.0239x; 1.0002x over previous
//
#include <hip/hip_runtime.h>

// GAT layer: B=8, N=2048, Fin=Fout=64
// k1 : Wh=h@W (MFMA) stored in MFMA-B-fragment order (whF) + s,t fp32. grid 256.
// k2 : masked softmax + P@Wh, 32 rows/block (grid 512, LB(256,2) -- best config).
//      adj loaded directly, NONTEMPORAL (via ext_vector int4 alias -- HIP int4 is a
//      class and rejected by the builtin), explicit 2-deep register prefetch:
//      iters 0/1 issued BEFORE the exp-table phase (table work hides under first
//      HBM round-trip); iter s+2 issued at top of iter s (fixed lookahead).
//      p = adj ? max(al*e^t, cl*e^{a t}) : 0; z via a 5th "ones-column" MFMA.

#define ALPHA 0.2f

typedef __attribute__((ext_vector_type(8))) short  short8;
typedef __attribute__((ext_vector_type(4))) float  f32x4;
typedef __attribute__((ext_vector_type(4))) int    i32x4;

static __device__ __forceinline__ unsigned short f2bf(float f) {
    unsigned u = __builtin_bit_cast(unsigned, f);
    u += 0x7fffu + ((u >> 16) & 1u);   // round-to-nearest-even
    return (unsigned short)(u >> 16);
}

// two f32 -> packed bf16x2 (lo in low half), round-half-up
static __device__ __forceinline__ unsigned pack_bf2(float lo, float hi) {
    unsigned ulo = __builtin_bit_cast(unsigned, lo) + 0x8000u;
    unsigned uhi = __builtin_bit_cast(unsigned, hi) + 0x8000u;
    return __builtin_amdgcn_perm(uhi, ulo, 0x07060302);
}

static __device__ __forceinline__ i32x4 ntload4(const int* p) {
    return __builtin_nontemporal_load((const i32x4*)p);
}

// ---------------- k1: Wh + s,t (unchanged) ----------------
__global__ __launch_bounds__(256) void k1(
    const float* __restrict__ h, const float* __restrict__ W,
    const float* __restrict__ a, uint4* __restrict__ whF,
    float* __restrict__ sw, float* __restrict__ tw)
{
    __shared__ float W_l[64 * 65];
    __shared__ float wa[128];
    __shared__ float tile[4 * 16 * 65];

    const int tid = threadIdx.x;
    const int lane = tid & 63, wv = tid >> 6;
    const int im   = lane & 15, kq = lane >> 4;

    #pragma unroll
    for (int k = 0; k < 16; ++k) {
        int e = tid + 256 * k;
        W_l[(e >> 6) * 65 + (e & 63)] = W[e];
    }
    __syncthreads();

    if (tid < 128) {
        int f = tid & 63;
        const float* ap = a + (tid >> 6) * 64;
        float acc = 0.f;
        #pragma unroll 8
        for (int o = 0; o < 64; ++o) acc += W_l[f * 65 + o] * ap[o];
        wa[tid] = acc;
    }
    __syncthreads();

    short8 bf[4][2];
    #pragma unroll
    for (int nb = 0; nb < 4; ++nb)
        #pragma unroll
        for (int ks = 0; ks < 2; ++ks)
            #pragma unroll
            for (int u = 0; u < 8; ++u)
                bf[nb][ks][u] = (short)f2bf(W_l[(ks * 32 + kq * 8 + u) * 65 + nb * 16 + im]);

    const int row0 = blockIdx.x * 64 + wv * 16;
    const float* hrow = h + (size_t)(row0 + im) * 64;

    float hv[2][8];
    short8 af[2];
    float sp = 0.f, tp = 0.f;
    #pragma unroll
    for (int ks = 0; ks < 2; ++ks) {
        float4 A = *(const float4*)(hrow + ks * 32 + kq * 8);
        float4 Bv = *(const float4*)(hrow + ks * 32 + kq * 8 + 4);
        hv[ks][0] = A.x;  hv[ks][1] = A.y;  hv[ks][2] = A.z;  hv[ks][3] = A.w;
        hv[ks][4] = Bv.x; hv[ks][5] = Bv.y; hv[ks][6] = Bv.z; hv[ks][7] = Bv.w;
        #pragma unroll
        for (int u = 0; u < 8; ++u) {
            int f = ks * 32 + kq * 8 + u;
            sp += hv[ks][u] * wa[f];
            tp += hv[ks][u] * wa[64 + f];
            af[ks][u] = (short)f2bf(hv[ks][u]);
        }
    }
    sp += __shfl_xor(sp, 16, 64); sp += __shfl_xor(sp, 32, 64);
    tp += __shfl_xor(tp, 16, 64); tp += __shfl_xor(tp, 32, 64);
    if (lane < 16) {
        sw[row0 + lane] = sp;
        tw[row0 + lane] = tp;
    }

    f32x4 acc[4] = {{0.f,0.f,0.f,0.f},{0.f,0.f,0.f,0.f},{0.f,0.f,0.f,0.f},{0.f,0.f,0.f,0.f}};
    #pragma unroll
    for (int ks = 0; ks < 2; ++ks)
        #pragma unroll
        for (int nb = 0; nb < 4; ++nb)
            acc[nb] = __builtin_amdgcn_mfma_f32_16x16x32_bf16(af[ks], bf[nb][ks], acc[nb], 0, 0, 0);

    #pragma unroll
    for (int nb = 0; nb < 4; ++nb)
        #pragma unroll
        for (int r = 0; r < 4; ++r)
            tile[wv * 1040 + (kq * 4 + r) * 65 + nb * 16 + im] = acc[nb][r];
    __syncthreads();

    // ---- store Wh in MFMA-B-fragment order ----
    {
        const int blk_row0 = blockIdx.x * 64;
        const int bb2 = blk_row0 >> 11;
        const int c_base = (blk_row0 & 2047) >> 5;
        #pragma unroll
        for (int k = 0; k < 2; ++k) {
            int e = tid + 256 * k;
            int l = e & 63, ot = (e >> 6) & 3, cl_ = e >> 8;
            int o = ot * 16 + (l & 15);
            int jb = cl_ * 32 + (l >> 4) * 8;
            unsigned d0, d1, d2, d3;
            {
                int j0 = jb;
                d0 = pack_bf2(tile[(j0 >> 4) * 1040 + (j0 & 15) * 65 + o],
                              tile[(j0 >> 4) * 1040 + ((j0 & 15) + 1) * 65 + o]);
                j0 = jb + 2;
                d1 = pack_bf2(tile[(j0 >> 4) * 1040 + (j0 & 15) * 65 + o],
                              tile[(j0 >> 4) * 1040 + ((j0 & 15) + 1) * 65 + o]);
                j0 = jb + 4;
                d2 = pack_bf2(tile[(j0 >> 4) * 1040 + (j0 & 15) * 65 + o],
                              tile[(j0 >> 4) * 1040 + ((j0 & 15) + 1) * 65 + o]);
                j0 = jb + 6;
                d3 = pack_bf2(tile[(j0 >> 4) * 1040 + (j0 & 15) * 65 + o],
                              tile[(j0 >> 4) * 1040 + ((j0 & 15) + 1) * 65 + o]);
            }
            uint4 val = {d0, d1, d2, d3};
            whF[(size_t)(((bb2 * 64 + c_base + cl_) * 4 + ot)) * 64 + l] = val;
        }
    }
}

// ---------------- k2: masked softmax + P@Wh ----------------
// grid 512 (b, i0: 32 rows) x 256 thr; wave = 512-j stripe, 2 row-tiles of 16.
__global__ __launch_bounds__(256, 2) void k2_attn(
    const int* __restrict__ adj, const uint4* __restrict__ whF,
    const float* __restrict__ sw, const float* __restrict__ tw,
    float* __restrict__ out)
{
    __shared__ float eB[2048];
    __shared__ float eD[2048];
    __shared__ float cpart[4 * 2176];   // [wv][row 0..31][col 0..67]; col 64 = z

    const int tid  = threadIdx.x;
    const int lane = tid & 63, wv = tid >> 6;
    const int im   = lane & 15, kq = lane >> 4;
    const int b    = blockIdx.x >> 6;
    const int i0   = (blockIdx.x & 63) << 5;

    const int j00 = wv * 512 + kq * 8;
    // adj row pointers (int granularity; int4-steps = 4 ints). iter s: +s*32 ints.
    const int* arow0 = adj + (size_t)(b * 2048 + i0 + im) * 2048 + j00;
    const int* arow1 = adj + (size_t)(b * 2048 + i0 + 16 + im) * 2048 + j00;

    // ---- 2-deep adj prefetch, issued BEFORE the exp-table phase ----
    i32x4 f0A[2], f0B[2], f1A[2], f1B[2];
    f0A[0] = ntload4(arow0);       f0B[0] = ntload4(arow0 + 4);
    f1A[0] = ntload4(arow1);       f1B[0] = ntload4(arow1 + 4);
    f0A[1] = ntload4(arow0 + 32);  f0B[1] = ntload4(arow0 + 36);
    f1A[1] = ntload4(arow1 + 32);  f1B[1] = ntload4(arow1 + 36);

    // exp tables: eB[j]=exp(t_j), eD[j]=exp(ALPHA*t_j)  (hides under prefetch latency)
    {
        const float4* tp4 = (const float4*)(tw + (size_t)b * 2048);
        float4 t0 = tp4[tid], t1 = tp4[tid + 256];
        float4 e0 = {__expf(t0.x), __expf(t0.y), __expf(t0.z), __expf(t0.w)};
        float4 e1 = {__expf(t1.x), __expf(t1.y), __expf(t1.z), __expf(t1.w)};
        float4 f0 = {__expf(ALPHA*t0.x), __expf(ALPHA*t0.y), __expf(ALPHA*t0.z), __expf(ALPHA*t0.w)};
        float4 f1 = {__expf(ALPHA*t1.x), __expf(ALPHA*t1.y), __expf(ALPHA*t1.z), __expf(ALPHA*t1.w)};
        *(float4*)&eB[tid * 4] = e0;  *(float4*)&eB[(tid + 256) * 4] = e1;
        *(float4*)&eD[tid * 4] = f0;  *(float4*)&eD[(tid + 256) * 4] = f1;
    }

    const float sl0 = sw[b * 2048 + i0 + im];
    const float sl1 = sw[b * 2048 + i0 + 16 + im];
    const float al0 = __expf(sl0), cl0 = __expf(ALPHA * sl0);
    const float al1 = __expf(sl1), cl1 = __expf(ALPHA * sl1);

    const uint4* wbase = whF + (size_t)((b * 64 + wv * 16) * 4) * 64 + lane;

    // ones-column B-fragment: B[k][0] = 1, else 0  ->  D[i][0] = row sum
    short8 onesf;
    {
        const short ov = (im == 0) ? (short)0x3F80 : (short)0;
        #pragma unroll
        for (int u = 0; u < 8; ++u) onesf[u] = ov;
    }

    __syncthreads();

    f32x4 acc0 = {0.f,0.f,0.f,0.f}, acc1 = {0.f,0.f,0.f,0.f};
    f32x4 acc2 = {0.f,0.f,0.f,0.f}, acc3 = {0.f,0.f,0.f,0.f};
    f32x4 acc4 = {0.f,0.f,0.f,0.f}, acc5 = {0.f,0.f,0.f,0.f};
    f32x4 acc6 = {0.f,0.f,0.f,0.f}, acc7 = {0.f,0.f,0.f,0.f};
    f32x4 az0  = {0.f,0.f,0.f,0.f}, az1  = {0.f,0.f,0.f,0.f};

    #pragma unroll
    for (int s = 0; s < 16; ++s) {
        // consume prefetched slot (s is compile-time: static indexing, no scratch)
        const i32x4 a0A = f0A[s & 1], a0B = f0B[s & 1];
        const i32x4 a1A = f1A[s & 1], a1B = f1B[s & 1];
        // refill slot with iter s+2 (fixed 2-iter lookahead)
        if (s < 14) {
            f0A[s & 1] = ntload4(arow0 + (s + 2) * 32);
            f0B[s & 1] = ntload4(arow0 + (s + 2) * 32 + 4);
            f1A[s & 1] = ntload4(arow1 + (s + 2) * 32);
            f1B[s & 1] = ntload4(arow1 + (s + 2) * 32 + 4);
        }

        const uint4 w0 = wbase[(s * 4 + 0) * 64];
        const uint4 w1 = wbase[(s * 4 + 1) * 64];
        const uint4 w2 = wbase[(s * 4 + 2) * 64];
        const uint4 w3 = wbase[(s * 4 + 3) * 64];

        const float4 bA  = *(const float4*)&eB[j00 + s * 32];
        const float4 bBv = *(const float4*)&eB[j00 + s * 32 + 4];
        const float4 dA  = *(const float4*)&eD[j00 + s * 32];
        const float4 dBv = *(const float4*)&eD[j00 + s * 32 + 4];

        // tile 0 (rows i0..i0+15):  p = adj ? max(al*e^t, cl*e^{a t}) : 0
        float p0 = fmaxf(al0 * bA.x,  cl0 * dA.x);   p0 = a0A.x ? p0 : 0.f;
        float p1 = fmaxf(al0 * bA.y,  cl0 * dA.y);   p1 = a0A.y ? p1 : 0.f;
        float p2 = fmaxf(al0 * bA.z,  cl0 * dA.z);   p2 = a0A.z ? p2 : 0.f;
        float p3 = fmaxf(al0 * bA.w,  cl0 * dA.w);   p3 = a0A.w ? p3 : 0.f;
        float p4 = fmaxf(al0 * bBv.x, cl0 * dBv.x);  p4 = a0B.x ? p4 : 0.f;
        float p5 = fmaxf(al0 * bBv.y, cl0 * dBv.y);  p5 = a0B.y ? p5 : 0.f;
        float p6 = fmaxf(al0 * bBv.z, cl0 * dBv.z);  p6 = a0B.z ? p6 : 0.f;
        float p7 = fmaxf(al0 * bBv.w, cl0 * dBv.w);  p7 = a0B.w ? p7 : 0.f;

        int4 ai0;
        ai0.x = (int)pack_bf2(p0, p1);
        ai0.y = (int)pack_bf2(p2, p3);
        ai0.z = (int)pack_bf2(p4, p5);
        ai0.w = (int)pack_bf2(p6, p7);
        const short8 af0 = __builtin_bit_cast(short8, ai0);

        // tile 1 (rows i0+16..i0+31)
        float q0 = fmaxf(al1 * bA.x,  cl1 * dA.x);   q0 = a1A.x ? q0 : 0.f;
        float q1 = fmaxf(al1 * bA.y,  cl1 * dA.y);   q1 = a1A.y ? q1 : 0.f;
        float q2 = fmaxf(al1 * bA.z,  cl1 * dA.z);   q2 = a1A.z ? q2 : 0.f;
        float q3 = fmaxf(al1 * bA.w,  cl1 * dA.w);   q3 = a1A.w ? q3 : 0.f;
        float q4 = fmaxf(al1 * bBv.x, cl1 * dBv.x);  q4 = a1B.x ? q4 : 0.f;
        float q5 = fmaxf(al1 * bBv.y, cl1 * dBv.y);  q5 = a1B.y ? q5 : 0.f;
        float q6 = fmaxf(al1 * bBv.z, cl1 * dBv.z);  q6 = a1B.z ? q6 : 0.f;
        float q7 = fmaxf(al1 * bBv.w, cl1 * dBv.w);  q7 = a1B.w ? q7 : 0.f;

        int4 ai1;
        ai1.x = (int)pack_bf2(q0, q1);
        ai1.y = (int)pack_bf2(q2, q3);
        ai1.z = (int)pack_bf2(q4, q5);
        ai1.w = (int)pack_bf2(q6, q7);
        const short8 af1 = __builtin_bit_cast(short8, ai1);

        acc0 = __builtin_amdgcn_mfma_f32_16x16x32_bf16(af0, __builtin_bit_cast(short8, w0), acc0, 0, 0, 0);
        acc1 = __builtin_amdgcn_mfma_f32_16x16x32_bf16(af0, __builtin_bit_cast(short8, w1), acc1, 0, 0, 0);
        acc2 = __builtin_amdgcn_mfma_f32_16x16x32_bf16(af0, __builtin_bit_cast(short8, w2), acc2, 0, 0, 0);
        acc3 = __builtin_amdgcn_mfma_f32_16x16x32_bf16(af0, __builtin_bit_cast(short8, w3), acc3, 0, 0, 0);
        az0  = __builtin_amdgcn_mfma_f32_16x16x32_bf16(af0, onesf, az0, 0, 0, 0);

        acc4 = __builtin_amdgcn_mfma_f32_16x16x32_bf16(af1, __builtin_bit_cast(short8, w0), acc4, 0, 0, 0);
        acc5 = __builtin_amdgcn_mfma_f32_16x16x32_bf16(af1, __builtin_bit_cast(short8, w1), acc5, 0, 0, 0);
        acc6 = __builtin_amdgcn_mfma_f32_16x16x32_bf16(af1, __builtin_bit_cast(short8, w2), acc6, 0, 0, 0);
        acc7 = __builtin_amdgcn_mfma_f32_16x16x32_bf16(af1, __builtin_bit_cast(short8, w3), acc7, 0, 0, 0);
        az1  = __builtin_amdgcn_mfma_f32_16x16x32_bf16(af1, onesf, az1, 0, 0, 0);
    }

    #pragma unroll
    for (int r = 0; r < 4; ++r) {
        const int row = kq * 4 + r;
        float* cp0 = &cpart[wv * 2176 + row * 68];
        cp0[ 0 + im] = acc0[r];
        cp0[16 + im] = acc1[r];
        cp0[32 + im] = acc2[r];
        cp0[48 + im] = acc3[r];
        float* cp1 = &cpart[wv * 2176 + (16 + row) * 68];
        cp1[ 0 + im] = acc4[r];
        cp1[16 + im] = acc5[r];
        cp1[32 + im] = acc6[r];
        cp1[48 + im] = acc7[r];
        if (im == 0) { cp0[64] = az0[r]; cp1[64] = az1[r]; }
    }
    __syncthreads();

    // epilogue: 2 float4 outputs per thread
    #pragma unroll
    for (int k = 0; k < 2; ++k) {
        const int idx4 = tid + 256 * k;        // 0..511
        const int i  = idx4 >> 4;              // 0..31
        const int oc = (idx4 & 15) << 2;       // 0,4,..,60
        const float4 s0 = *(const float4*)&cpart[0 * 2176 + i * 68 + oc];
        const float4 s1 = *(const float4*)&cpart[1 * 2176 + i * 68 + oc];
        const float4 s2 = *(const float4*)&cpart[2 * 2176 + i * 68 + oc];
        const float4 s3 = *(const float4*)&cpart[3 * 2176 + i * 68 + oc];
        float z = cpart[0 * 2176 + i * 68 + 64] + cpart[1 * 2176 + i * 68 + 64]
                + cpart[2 * 2176 + i * 68 + 64] + cpart[3 * 2176 + i * 68 + 64];
        if (z == 0.f) z = 1.f;
        const float inv = 1.f / z;
        float4 rv;
        rv.x = ((s0.x + s1.x) + (s2.x + s3.x)) * inv;
        rv.y = ((s0.y + s1.y) + (s2.y + s3.y)) * inv;
        rv.z = ((s0.z + s1.z) + (s2.z + s3.z)) * inv;
        rv.w = ((s0.w + s1.w) + (s2.w + s3.w)) * inv;
        rv.x = rv.x > 0.f ? rv.x : expm1f(rv.x);
        rv.y = rv.y > 0.f ? rv.y : expm1f(rv.y);
        rv.z = rv.z > 0.f ? rv.z : expm1f(rv.z);
        rv.w = rv.w > 0.f ? rv.w : expm1f(rv.w);
        *(float4*)(out + ((size_t)(b * 2048 + i0 + i)) * 64 + oc) = rv;
    }
}

extern "C" void kernel_launch(void* const* d_in, const int* in_sizes, int n_in,
                              void* d_out, int out_size, void* d_ws, size_t ws_size,
                              hipStream_t stream) {
    const float* h   = (const float*)d_in[0];
    const int*   adj = (const int*)d_in[1];
    const float* W   = (const float*)d_in[2];
    const float* a   = (const float*)d_in[3];
    float* out = (float*)d_out;

    uint4* whF = (uint4*)d_ws;                                           // 2 MiB
    float* sw  = (float*)((char*)d_ws + 2097152);                        // 64 KiB
    float* tw  = (float*)((char*)d_ws + 2097152 + 65536);                // 64 KiB

    hipLaunchKernelGGL(k1, dim3(256), dim3(256), 0, stream, h, W, a, whF, sw, tw);
    hipLaunchKernelGGL(k2_attn, dim3(512), dim3(256), 0, stream,
                       adj, whF, sw, tw, out);
}